// Round 8
// baseline (41.846 us; speedup 1.0000x reference)
//
#include <hip/hip_runtime.h>

// GALNLLLoss2d: fused 2x2 Cholesky-solve + log K1 Bessel NLL, mean-reduced.
// Inputs (f32): loc[B,2], m[B,2], L[B,2,2] (lower-tri, positive diag), x[B,2]
// Output: single f32 = -mean(log_prob)
// R8: R4 loader (float2 x3 + float4 per row) with an honest 4-row batch:
//     16 loads issued into named locals before any compute (staged vmcnt),
//     __launch_bounds__(256,8) pins VGPR<=64 so full 32 waves/CU is kept.
//     Two-kernel deterministic reduce (single-kernel finish costs ~65us in
//     agent-scope L2 wb/inv -- R3/R6).

#define C_LOG2   0.6931471805599453f
#define C_LOG2PI 1.8378770664093453f
#define C_LN2    0.69314718055994530942f

__device__ __forceinline__ float fast_log(float v) {
    return __builtin_amdgcn_logf(v) * C_LN2;   // v_log_f32 is log2
}

__device__ __forceinline__ float gal_row(
    float2 l, float2 m, float2 x, float4 L)
{
    const float La = L.x, Lb = L.z, Lc = L.w;
    const float ia = __builtin_amdgcn_rcpf(La);
    const float ic = __builtin_amdgcn_rcpf(Lc);
    const float d0 = x.x - l.x, d1 = x.y - l.y;
    // y = L^{-1} v (forward substitution); v^T Sinv w = (L^{-1}v)·(L^{-1}w)
    const float ym0 = m.x * ia;
    const float ym1 = (m.y - Lb * ym0) * ic;
    const float yx0 = d0 * ia;
    const float yx1 = (d1 - Lb * yx0) * ic;
    const float qm  = ym0 * ym0 + ym1 * ym1;   // m^T Sinv m
    const float qx  = yx0 * yx0 + yx1 * yx1;   // diff^T Sinv diff
    const float qxm = yx0 * ym0 + yx1 * ym1;   // diff^T Sinv m
    const float s = 2.0f + qm;
    const float z = sqrtf(s * qx);

    // Branchless A&S 9.8.3/9.8.7/9.8.8 with clamped safe args.
    const float zs = fminf(z, 2.0f);
    float t = zs * 0.26666666666f;  // z/3.75
    t = t * t;
    const float i1 = zs * (0.5f + t * (0.87890594f + t * (0.51498869f
                   + t * (0.15084934f + t * (0.02658733f + t * (0.00301532f
                   + t * 0.00032411f))))));
    const float t2 = zs * zs * 0.25f;
    const float zk1 = zs * fast_log(zs * 0.5f) * i1 + 1.0f + t2 * (0.15443144f
                    + t2 * (-0.67278579f + t2 * (-0.18156897f
                    + t2 * (-0.01919402f + t2 * (-0.00110404f
                    + t2 * (-0.00004686f))))));
    const float zl = fmaxf(z, 2.0f);
    const float u = 2.0f * __builtin_amdgcn_rcpf(zl);
    const float poly = 1.25331414f + u * (0.23498619f + u * (-0.03655620f
                     + u * (0.01504268f + u * (-0.00780353f + u * (0.00325614f
                     + u * (-0.00068245f))))));
    const bool small = (z <= 2.0f);
    // Fold: -log(a*c) + 0.5*log(qx/s) + log(kve1) - z
    //   small: = log( zk1 / (s*a*c) )                 [z/zs cancels]
    //   large: = log( poly*sqrt(z) / (s*a*c) ) - z
    const float arg = small ? zk1 : poly * sqrtf(z);
    const float tail = small ? 0.0f : z;
    return C_LOG2 + qxm - C_LOG2PI
         + fast_log(arg * __builtin_amdgcn_rcpf(s * La * Lc)) - tail;
}

__global__ __launch_bounds__(256, 8) void gal_main_kernel(
    const float2* __restrict__ loc2, const float2* __restrict__ m2,
    const float4* __restrict__ L4,   const float2* __restrict__ x2,
    float* __restrict__ partial, int n)
{
    float acc = 0.0f;
    const int stride = gridDim.x * blockDim.x;
    int i = blockIdx.x * blockDim.x + threadIdx.x;
    // 4-row batch: all 16 loads issued into distinct locals before compute.
    for (; i + 3 * stride < n; i += 4 * stride) {
        const int i1 = i + stride, i2 = i + 2 * stride, i3 = i + 3 * stride;
        const float2 l0 = loc2[i],  mm0 = m2[i],  xx0 = x2[i];
        const float4 A0 = L4[i];
        const float2 l1 = loc2[i1], mm1 = m2[i1], xx1 = x2[i1];
        const float4 A1 = L4[i1];
        const float2 l2 = loc2[i2], mm2 = m2[i2], xx2 = x2[i2];
        const float4 A2 = L4[i2];
        const float2 l3 = loc2[i3], mm3 = m2[i3], xx3 = x2[i3];
        const float4 A3 = L4[i3];
        acc += gal_row(l0, mm0, xx0, A0);
        acc += gal_row(l1, mm1, xx1, A1);
        acc += gal_row(l2, mm2, xx2, A2);
        acc += gal_row(l3, mm3, xx3, A3);
    }
    for (; i < n; i += stride)
        acc += gal_row(loc2[i], m2[i], x2[i], L4[i]);

    // wave64 down-reduce (f32), then cross-wave via LDS
    #pragma unroll
    for (int off = 32; off > 0; off >>= 1)
        acc += __shfl_down(acc, off);
    __shared__ float smem[4];
    const int lane = threadIdx.x & 63;
    const int wid  = threadIdx.x >> 6;
    if (lane == 0) smem[wid] = acc;
    __syncthreads();
    if (threadIdx.x == 0)
        partial[blockIdx.x] = smem[0] + smem[1] + smem[2] + smem[3];
}

__global__ __launch_bounds__(256) void gal_final_kernel(
    const float* __restrict__ partial, int nblocks,
    float* __restrict__ out, double inv_n)
{
    double acc = 0.0;
    for (int i = threadIdx.x; i < nblocks; i += 256)
        acc += (double)partial[i];
    #pragma unroll
    for (int off = 32; off > 0; off >>= 1)
        acc += __shfl_down(acc, off);
    __shared__ double smem[4];
    const int lane = threadIdx.x & 63;
    const int wid  = threadIdx.x >> 6;
    if (lane == 0) smem[wid] = acc;
    __syncthreads();
    if (threadIdx.x == 0)
        out[0] = (float)(-(smem[0] + smem[1] + smem[2] + smem[3]) * inv_n);
}

extern "C" void kernel_launch(void* const* d_in, const int* in_sizes, int n_in,
                              void* d_out, int out_size, void* d_ws, size_t ws_size,
                              hipStream_t stream) {
    const float* loc = (const float*)d_in[0];
    const float* m   = (const float*)d_in[1];
    const float* L   = (const float*)d_in[2];
    const float* x   = (const float*)d_in[3];
    const int n = in_sizes[0] / 2;       // B rows

    int nblocks = 2048;  // 524288 threads; n/stride = 8 -> exactly 2 batches
    const size_t need = (size_t)nblocks * sizeof(float);
    if (ws_size < need) nblocks = (int)(ws_size / sizeof(float));
    float* partial = (float*)d_ws;

    gal_main_kernel<<<nblocks, 256, 0, stream>>>(
        (const float2*)loc, (const float2*)m, (const float4*)L,
        (const float2*)x, partial, n);
    gal_final_kernel<<<1, 256, 0, stream>>>(partial, nblocks, (float*)d_out,
                                            1.0 / (double)n);
}

// Round 9
// 35.334 us; speedup vs baseline: 1.1843x; 1.1843x over previous
//
#include <hip/hip_runtime.h>

// GALNLLLoss2d: fused 2x2 Cholesky-solve + log K1 Bessel NLL, mean-reduced.
// Inputs (f32): loc[B,2], m[B,2], L[B,2,2] (lower-tri, positive diag), x[B,2]
// Output: single f32 = -mean(log_prob)
// R9: R4 structure (best measured: float2/float4 per-row loads, native
//     v_rcp/v_log, 2-deep batch, two-kernel deterministic reduce) with
//     4096 blocks -> exactly one 2-deep batch per thread, finer tail-stagger.
//     Single-kernel finishes cost ~65us in agent-scope L2 wb/inv (R3/R6);
//     4-row batching hurts L3 residency (R8: FETCH 82->91 MB).

#define C_LOG2   0.6931471805599453f
#define C_LOG2PI 1.8378770664093453f
#define C_LN2    0.69314718055994530942f

__device__ __forceinline__ float fast_log(float v) {
    return __builtin_amdgcn_logf(v) * C_LN2;   // v_log_f32 is log2
}

__device__ __forceinline__ float gal_row(
    float2 l, float2 m, float2 x, float4 L)
{
    const float La = L.x, Lb = L.z, Lc = L.w;
    const float ia = __builtin_amdgcn_rcpf(La);
    const float ic = __builtin_amdgcn_rcpf(Lc);
    const float d0 = x.x - l.x, d1 = x.y - l.y;
    // y = L^{-1} v (forward substitution); v^T Sinv w = (L^{-1}v)·(L^{-1}w)
    const float ym0 = m.x * ia;
    const float ym1 = (m.y - Lb * ym0) * ic;
    const float yx0 = d0 * ia;
    const float yx1 = (d1 - Lb * yx0) * ic;
    const float qm  = ym0 * ym0 + ym1 * ym1;   // m^T Sinv m
    const float qx  = yx0 * yx0 + yx1 * yx1;   // diff^T Sinv diff
    const float qxm = yx0 * ym0 + yx1 * ym1;   // diff^T Sinv m
    const float s = 2.0f + qm;
    const float z = sqrtf(s * qx);

    // Branchless A&S 9.8.3/9.8.7/9.8.8 with clamped safe args.
    const float zs = fminf(z, 2.0f);
    float t = zs * 0.26666666666f;  // z/3.75
    t = t * t;
    const float i1 = zs * (0.5f + t * (0.87890594f + t * (0.51498869f
                   + t * (0.15084934f + t * (0.02658733f + t * (0.00301532f
                   + t * 0.00032411f))))));
    const float t2 = zs * zs * 0.25f;
    const float zk1 = zs * fast_log(zs * 0.5f) * i1 + 1.0f + t2 * (0.15443144f
                    + t2 * (-0.67278579f + t2 * (-0.18156897f
                    + t2 * (-0.01919402f + t2 * (-0.00110404f
                    + t2 * (-0.00004686f))))));
    const float zl = fmaxf(z, 2.0f);
    const float u = 2.0f * __builtin_amdgcn_rcpf(zl);
    const float poly = 1.25331414f + u * (0.23498619f + u * (-0.03655620f
                     + u * (0.01504268f + u * (-0.00780353f + u * (0.00325614f
                     + u * (-0.00068245f))))));
    const bool small = (z <= 2.0f);
    // Fold: -log(a*c) + 0.5*log(qx/s) + log(kve1) - z
    //   small: = log( zk1 / (s*a*c) )                 [z/zs cancels]
    //   large: = log( poly*sqrt(z) / (s*a*c) ) - z
    const float arg = small ? zk1 : poly * sqrtf(z);
    const float tail = small ? 0.0f : z;
    return C_LOG2 + qxm - C_LOG2PI
         + fast_log(arg * __builtin_amdgcn_rcpf(s * La * Lc)) - tail;
}

__global__ __launch_bounds__(256) void gal_main_kernel(
    const float2* __restrict__ loc2, const float2* __restrict__ m2,
    const float4* __restrict__ L4,   const float2* __restrict__ x2,
    float* __restrict__ partial, int n)
{
    float acc = 0.0f;
    const int stride = gridDim.x * blockDim.x;
    int i = blockIdx.x * blockDim.x + threadIdx.x;
    // 2-deep unconditional batch: issue all 8 loads, then compute both rows.
    for (; i + stride < n; i += 2 * stride) {
        const int j = i + stride;
        const float2 l0 = loc2[i], mm0 = m2[i], xx0 = x2[i];
        const float4 A0 = L4[i];
        const float2 l1 = loc2[j], mm1 = m2[j], xx1 = x2[j];
        const float4 A1 = L4[j];
        acc += gal_row(l0, mm0, xx0, A0);
        acc += gal_row(l1, mm1, xx1, A1);
    }
    if (i < n)
        acc += gal_row(loc2[i], m2[i], x2[i], L4[i]);

    // wave64 down-reduce (f32), then cross-wave via LDS
    #pragma unroll
    for (int off = 32; off > 0; off >>= 1)
        acc += __shfl_down(acc, off);
    __shared__ float smem[4];
    const int lane = threadIdx.x & 63;
    const int wid  = threadIdx.x >> 6;
    if (lane == 0) smem[wid] = acc;
    __syncthreads();
    if (threadIdx.x == 0)
        partial[blockIdx.x] = smem[0] + smem[1] + smem[2] + smem[3];
}

__global__ __launch_bounds__(256) void gal_final_kernel(
    const float* __restrict__ partial, int nblocks,
    float* __restrict__ out, double inv_n)
{
    double acc = 0.0;
    for (int i = threadIdx.x; i < nblocks; i += 256)
        acc += (double)partial[i];
    #pragma unroll
    for (int off = 32; off > 0; off >>= 1)
        acc += __shfl_down(acc, off);
    __shared__ double smem[4];
    const int lane = threadIdx.x & 63;
    const int wid  = threadIdx.x >> 6;
    if (lane == 0) smem[wid] = acc;
    __syncthreads();
    if (threadIdx.x == 0)
        out[0] = (float)(-(smem[0] + smem[1] + smem[2] + smem[3]) * inv_n);
}

extern "C" void kernel_launch(void* const* d_in, const int* in_sizes, int n_in,
                              void* d_out, int out_size, void* d_ws, size_t ws_size,
                              hipStream_t stream) {
    const float* loc = (const float*)d_in[0];
    const float* m   = (const float*)d_in[1];
    const float* L   = (const float*)d_in[2];
    const float* x   = (const float*)d_in[3];
    const int n = in_sizes[0] / 2;       // B rows

    int nblocks = 4096;  // 1,048,576 threads -> exactly one 2-deep batch each
    const size_t need = (size_t)nblocks * sizeof(float);
    if (ws_size < need) nblocks = (int)(ws_size / sizeof(float));
    float* partial = (float*)d_ws;

    gal_main_kernel<<<nblocks, 256, 0, stream>>>(
        (const float2*)loc, (const float2*)m, (const float4*)L,
        (const float2*)x, partial, n);
    gal_final_kernel<<<1, 256, 0, stream>>>(partial, nblocks, (float*)d_out,
                                            1.0 / (double)n);
}